// Round 2
// baseline (475.504 us; speedup 1.0000x reference)
//
#include <hip/hip_runtime.h>
#include <hip/hip_bf16.h>

#define B_DIM 128
#define S_DIM 512
#define D_DIM 1024
#define GEN_VV 50000
#define OUT_VV 50257

typedef float f32x4 __attribute__((ext_vector_type(4)));
typedef __bf16 bf16x8 __attribute__((ext_vector_type(8)));
typedef __bf16 bf16x4 __attribute__((ext_vector_type(4)));
typedef __bf16 bf16x2 __attribute__((ext_vector_type(2)));

// ---------------- K1: gate + x -> bf16 ----------------
__global__ __launch_bounds__(256) void k_gate(const float* __restrict__ x,
        const float* __restrict__ Wg, const float* __restrict__ bgate,
        __bf16* __restrict__ xb, float* __restrict__ interp) {
    __shared__ float red[4];
    const int b = blockIdx.x, t = threadIdx.x;
    float4 xv = reinterpret_cast<const float4*>(x + (size_t)b * D_DIM)[t];
    float4 wv = reinterpret_cast<const float4*>(Wg)[t];
    float dot = xv.x * wv.x + xv.y * wv.y + xv.z * wv.z + xv.w * wv.w;
    bf16x4 hb;
    hb[0] = (__bf16)xv.x; hb[1] = (__bf16)xv.y; hb[2] = (__bf16)xv.z; hb[3] = (__bf16)xv.w;
    reinterpret_cast<bf16x4*>(xb + (size_t)b * D_DIM)[t] = hb;
#pragma unroll
    for (int m = 32; m >= 1; m >>= 1) dot += __shfl_xor(dot, m);
    if ((t & 63) == 0) red[t >> 6] = dot;
    __syncthreads();
    if (t == 0) {
        float d = red[0] + red[1] + red[2] + red[3] + bgate[0];
        interp[b] = 1.0f / (1.0f + __expf(-d));
    }
}

// ---------------- K2: GEMM logits = x @ W_gen + b_gen (bf16 MFMA) ----------------
__global__ __launch_bounds__(256) void k_gemm(const __bf16* __restrict__ xb,
        const float* __restrict__ W, const float* __restrict__ bgen,
        float* __restrict__ logits) {
    __shared__ __align__(16) __bf16 As[128 * 40];  // [row][k] stride 40
    __shared__ __align__(16) __bf16 Ws[64 * 40];   // [n][k]  stride 40
    const int t = threadIdx.x;
    const int lane = t & 63;
    const int wv = t >> 6;
    const int wrow = wv * 32;
    const int g = lane >> 4;
    const int r16 = lane & 15;
    const int nb = blockIdx.x * 64;

    const int wk = (t >> 4) * 2;   // 0..30 even
    const int wn = (t & 15) * 4;   // 0..60
    const bool wval = (nb + wn) < GEN_VV;

    f32x4 acc[2][4];
#pragma unroll
    for (int i = 0; i < 2; i++)
#pragma unroll
        for (int j = 0; j < 4; j++) acc[i][j] = (f32x4){0.f, 0.f, 0.f, 0.f};

    for (int k0 = 0; k0 < D_DIM; k0 += 32) {
        // stage A (bf16 copy): 512 chunks of 8 bf16
        {
            const int r0 = t >> 2, kc0 = t & 3;
            *reinterpret_cast<uint4*>(&As[r0 * 40 + kc0 * 8]) =
                *reinterpret_cast<const uint4*>(&xb[(size_t)r0 * D_DIM + k0 + kc0 * 8]);
            const int c1 = t + 256;
            const int r1 = c1 >> 2, kc1 = c1 & 3;
            *reinterpret_cast<uint4*>(&As[r1 * 40 + kc1 * 8]) =
                *reinterpret_cast<const uint4*>(&xb[(size_t)r1 * D_DIM + k0 + kc1 * 8]);
        }
        // stage W (fp32 -> bf16, transpose into [n][k])
        {
            const float* p = W + (size_t)(k0 + wk) * GEN_VV + (nb + wn);
            float4 ra = wval ? *reinterpret_cast<const float4*>(p) : make_float4(0.f, 0.f, 0.f, 0.f);
            float4 rb = wval ? *reinterpret_cast<const float4*>(p + GEN_VV) : make_float4(0.f, 0.f, 0.f, 0.f);
            float fa[4] = {ra.x, ra.y, ra.z, ra.w};
            float fb[4] = {rb.x, rb.y, rb.z, rb.w};
#pragma unroll
            for (int j = 0; j < 4; j++) {
                bf16x2 pr;
                pr[0] = (__bf16)fa[j];
                pr[1] = (__bf16)fb[j];
                *reinterpret_cast<bf16x2*>(&Ws[(wn + j) * 40 + wk]) = pr;
            }
        }
        __syncthreads();
        bf16x8 af[2];
#pragma unroll
        for (int rf = 0; rf < 2; rf++) {
            bf16x4 lo = *reinterpret_cast<const bf16x4*>(&As[(wrow + rf * 16 + r16) * 40 + g * 4]);
            bf16x4 hi = *reinterpret_cast<const bf16x4*>(&As[(wrow + rf * 16 + r16) * 40 + 16 + g * 4]);
            af[rf] = __builtin_shufflevector(lo, hi, 0, 1, 2, 3, 4, 5, 6, 7);
        }
#pragma unroll
        for (int cf = 0; cf < 4; cf++) {
            bf16x4 lo = *reinterpret_cast<const bf16x4*>(&Ws[(cf * 16 + r16) * 40 + g * 4]);
            bf16x4 hi = *reinterpret_cast<const bf16x4*>(&Ws[(cf * 16 + r16) * 40 + 16 + g * 4]);
            bf16x8 bfr = __builtin_shufflevector(lo, hi, 0, 1, 2, 3, 4, 5, 6, 7);
#pragma unroll
            for (int rf = 0; rf < 2; rf++)
                acc[rf][cf] = __builtin_amdgcn_mfma_f32_16x16x32_bf16(af[rf], bfr, acc[rf][cf], 0, 0, 0);
        }
        __syncthreads();
    }
#pragma unroll
    for (int cf = 0; cf < 4; cf++) {
        const int col = nb + cf * 16 + r16;
        if (col < GEN_VV) {
            const float bg = bgen[col];
#pragma unroll
            for (int rf = 0; rf < 2; rf++) {
                const int row = wrow + rf * 16 + g * 4;
#pragma unroll
                for (int j = 0; j < 4; j++)
                    logits[(size_t)(row + j) * GEN_VV + col] = acc[rf][cf][j] + bg;
            }
        }
    }
}

// ---------------- K3: per-row max and 1/sum(exp) ----------------
__global__ __launch_bounds__(1024) void k_stats(const float* __restrict__ logits,
        float* __restrict__ stats) {
    __shared__ float red[16];
    __shared__ float bcast;
    const int b = blockIdx.x, t = threadIdx.x;
    const float4* row = reinterpret_cast<const float4*>(logits + (size_t)b * GEN_VV);
    float m = -1e30f;
    for (int i = t; i < GEN_VV / 4; i += 1024) {
        float4 v = row[i];
        m = fmaxf(m, fmaxf(fmaxf(v.x, v.y), fmaxf(v.z, v.w)));
    }
#pragma unroll
    for (int d = 32; d >= 1; d >>= 1) m = fmaxf(m, __shfl_xor(m, d));
    if ((t & 63) == 0) red[t >> 6] = m;
    __syncthreads();
    if (t == 0) {
        float M = red[0];
        for (int i = 1; i < 16; i++) M = fmaxf(M, red[i]);
        bcast = M;
    }
    __syncthreads();
    const float M = bcast;
    float s = 0.f;
    for (int i = t; i < GEN_VV / 4; i += 1024) {
        float4 v = row[i];
        s += __expf(v.x - M) + __expf(v.y - M) + __expf(v.z - M) + __expf(v.w - M);
    }
#pragma unroll
    for (int d = 32; d >= 1; d >>= 1) s += __shfl_xor(s, d);
    if ((t & 63) == 0) red[t >> 6] = s;
    __syncthreads();
    if (t == 0) {
        float S = 0.f;
        for (int i = 0; i < 16; i++) S += red[i];
        stats[2 * b] = M;
        stats[2 * b + 1] = 1.0f / S;
    }
}

// ---------------- CSR build for gen_to_out ----------------
__global__ __launch_bounds__(256) void k_hist(const int* __restrict__ g2o, int* __restrict__ hist) {
    int v = blockIdx.x * 256 + threadIdx.x;
    if (v < GEN_VV) atomicAdd(&hist[g2o[v]], 1);
}

__global__ __launch_bounds__(1024) void k_scan(const int* __restrict__ hist, int* __restrict__ offs) {
    __shared__ int sums[1024];
    const int t = threadIdx.x;
    const int lo = t * 50;
    const int hiS = (lo + 50 < OUT_VV) ? lo + 50 : OUT_VV;
    int s = 0;
    for (int i = lo; i < hiS; i++) s += hist[i];
    sums[t] = s;
    __syncthreads();
    for (int d = 1; d < 1024; d <<= 1) {
        int v = (t >= d) ? sums[t - d] : 0;
        __syncthreads();
        sums[t] += v;
        __syncthreads();
    }
    int run = sums[t] - s;  // exclusive prefix of this chunk
    const int hiW = (lo + 50 < OUT_VV + 1) ? lo + 50 : OUT_VV + 1;
    for (int i = lo; i < hiW; i++) {
        offs[i] = run;
        if (i < OUT_VV) run += hist[i];
    }
}

__global__ __launch_bounds__(256) void k_scatter(const int* __restrict__ g2o,
        const int* __restrict__ offs, int* __restrict__ cursor, int* __restrict__ items) {
    int v = blockIdx.x * 256 + threadIdx.x;
    if (v < GEN_VV) {
        int o = g2o[v];
        int slot = atomicAdd(&cursor[o], 1);
        items[offs[o] + slot] = v;
    }
}

// ---------------- K4: PT[v][b] = interp[b] * softmax prob ----------------
__global__ __launch_bounds__(256) void k_prob_t(const float* __restrict__ logits,
        const float* __restrict__ stats, const float* __restrict__ interp,
        float* __restrict__ PT) {
    __shared__ float tile[32][33];
    const int v0 = blockIdx.x * 32, b0 = blockIdx.y * 32;
    const int t = threadIdx.x;
    const int tv = t & 31, p = t >> 5;  // p: 0..7
#pragma unroll
    for (int q = 0; q < 4; q++) {
        const int b = b0 + p + 8 * q;
        const int v = v0 + tv;
        float val = 0.f;
        if (v < GEN_VV) {
            const float M = stats[2 * b], is = stats[2 * b + 1];
            val = __expf(logits[(size_t)b * GEN_VV + v] - M) * is * interp[b];
        }
        tile[tv][p + 8 * q] = val;
    }
    __syncthreads();
#pragma unroll
    for (int q = 0; q < 4; q++) {
        const int v = v0 + p + 8 * q;
        const int b = b0 + tv;
        if (v < GEN_VV) PT[(size_t)v * B_DIM + b] = tile[p + 8 * q][tv];
    }
}

// ---------------- K5: gather buckets -> out[b][o] ----------------
__global__ __launch_bounds__(256) void k_gather(const float* __restrict__ PT,
        const int* __restrict__ offs, const int* __restrict__ items,
        float* __restrict__ out) {
    __shared__ float tile[64][129];
    const int o0 = blockIdx.x * 64;
    const int t = threadIdx.x;
    const int grp = t >> 7;     // 0..1
    const int b = t & 127;
    for (int oi = grp; oi < 64; oi += 2) {
        const int o = o0 + oi;
        float acc = 0.f;
        if (o < OUT_VV) {
            const int base = offs[o], end = offs[o + 1];
            for (int idx = base; idx < end; idx++) {
                const int v = items[idx];
                acc += PT[(size_t)v * B_DIM + b];
            }
        }
        tile[oi][b] = acc;
    }
    __syncthreads();
    const int oj = t & 63, bb = t >> 6;
    for (int bp = 0; bp < 32; bp++) {
        const int bw = bp * 4 + bb;
        const int o = o0 + oj;
        if (o < OUT_VV) out[(size_t)bw * OUT_VV + o] = tile[oj][bw];
    }
}

// ---------------- K6: pointer scatter (atomics) ----------------
__global__ __launch_bounds__(256) void k_ptr(const float* __restrict__ alphas,
        const int* __restrict__ ctx, const int* __restrict__ i2o,
        const float* __restrict__ interp, float* __restrict__ out) {
    const int i = blockIdx.x * 256 + threadIdx.x;  // 65536 total
    const int b = i >> 9;
    const int o = i2o[ctx[i]];
    atomicAdd(&out[(size_t)b * OUT_VV + o], (1.0f - interp[b]) * alphas[i]);
}

extern "C" void kernel_launch(void* const* d_in, const int* in_sizes, int n_in,
                              void* d_out, int out_size, void* d_ws, size_t ws_size,
                              hipStream_t stream) {
    const float* x      = (const float*)d_in[0];
    const float* alphas = (const float*)d_in[1];
    const float* Wgate  = (const float*)d_in[2];
    const float* bgate  = (const float*)d_in[3];
    const float* Wgen   = (const float*)d_in[4];
    const float* bgen   = (const float*)d_in[5];
    const int*   ctx    = (const int*)d_in[6];
    const int*   g2o    = (const int*)d_in[7];
    const int*   i2o    = (const int*)d_in[8];
    float* out = (float*)d_out;

    // workspace layout (~26.7 MB total)
    char* w = (char*)d_ws;
    float* PT = (float*)w;          w += (size_t)GEN_VV * B_DIM * 4;   // 25,600,000 B
    __bf16* xb = (__bf16*)w;        w += (size_t)B_DIM * D_DIM * 2;    // 262,144 B
    float* interp = (float*)w;      w += 512;
    float* stats = (float*)w;       w += 1024;
    int* hist = (int*)w;            w += OUT_VV * 4;
    int* cursor = (int*)w;          w += OUT_VV * 4;
    int* offs = (int*)w;            w += (OUT_VV + 1) * 4;
    int* items = (int*)w;           w += GEN_VV * 4;

    float* logits = out;  // first 128*50000 floats of d_out used as scratch, fully overwritten later

    hipMemsetAsync(hist, 0, (size_t)2 * OUT_VV * sizeof(int), stream);  // hist + cursor (contiguous)

    k_gate<<<B_DIM, 256, 0, stream>>>(x, Wgate, bgate, xb, interp);
    k_gemm<<<(GEN_VV + 63) / 64, 256, 0, stream>>>(xb, Wgen, bgen, logits);
    k_stats<<<B_DIM, 1024, 0, stream>>>(logits, stats);
    k_hist<<<(GEN_VV + 255) / 256, 256, 0, stream>>>(g2o, hist);
    k_scan<<<1, 1024, 0, stream>>>(hist, offs);
    k_scatter<<<(GEN_VV + 255) / 256, 256, 0, stream>>>(g2o, offs, cursor, items);
    k_prob_t<<<dim3((GEN_VV + 31) / 32, B_DIM / 32), 256, 0, stream>>>(logits, stats, interp, PT);
    k_gather<<<(OUT_VV + 63) / 64, 256, 0, stream>>>(PT, offs, items, out);
    k_ptr<<<(B_DIM * S_DIM) / 256, 256, 0, stream>>>(alphas, ctx, i2o, interp, out);
}